// Round 2
// baseline (587.178 us; speedup 1.0000x reference)
//
#include <hip/hip_runtime.h>
#include <stdint.h>

typedef __bf16 bf16;
typedef __bf16 v8bf __attribute__((ext_vector_type(8)));
typedef __bf16 v4bf __attribute__((ext_vector_type(4)));
typedef float f32x4 __attribute__((ext_vector_type(4)));

#define MFMA16x16x32(a, b, c) __builtin_amdgcn_mfma_f32_16x16x32_bf16((a), (b), (c), 0, 0, 0)

__device__ __forceinline__ void async_ld16(const float* g, float* l) {
  __builtin_amdgcn_global_load_lds(
      (const __attribute__((address_space(1))) uint32_t*)g,
      (__attribute__((address_space(3))) uint32_t*)l, 16, 0, 0);
}

// ---------------- prep kernels ----------------
// Wt[o][k] (bf16, 128x256): k<128 -> (w_fuse[:, :128] @ w_h_pw)[o][k]
//                           k>=128 -> (w_fuse[:, 128:] @ w_v_pw)[o][k-128]
__global__ __launch_bounds__(64) void prep_wt(const float* __restrict__ wfuse,
                                              const float* __restrict__ whpw,
                                              const float* __restrict__ wvpw,
                                              bf16* __restrict__ Wt) {
  int id = blockIdx.x * 64 + threadIdx.x;  // 32768 total
  int o = id >> 8, k = id & 255, ki = k & 127;
  const float* fr = wfuse + o * 256 + (k < 128 ? 0 : 128);
  const float* pw = (k < 128) ? whpw : wvpw;
  float a0 = 0.f, a1 = 0.f, a2 = 0.f, a3 = 0.f;
#pragma unroll 8
  for (int j = 0; j < 128; j += 4) {
    a0 = fmaf(fr[j + 0], pw[(j + 0) * 128 + ki], a0);
    a1 = fmaf(fr[j + 1], pw[(j + 1) * 128 + ki], a1);
    a2 = fmaf(fr[j + 2], pw[(j + 2) * 128 + ki], a2);
    a3 = fmaf(fr[j + 3], pw[(j + 3) * 128 + ki], a3);
  }
  Wt[o * 256 + k] = (bf16)((a0 + a1) + (a2 + a3));
}

__global__ void prep_dm(const float* __restrict__ wdm1,
                        const float* __restrict__ wdm2,
                        bf16* __restrict__ W1, bf16* __restrict__ W2) {
  int id = blockIdx.x * 256 + threadIdx.x;  // 8192
  if (id < 4096) W1[id] = (bf16)wdm1[id];
  else           W2[id - 4096] = (bf16)wdm2[id - 4096];
}

// ---------------- fused main kernel ----------------
// 512 blocks = (b:2)x(hi:64)x(wchunk:4); tile 5 rows x 80 cols = 400 pos.
// K streamed as 8 chunks of 16 channels; x chunk DMA'd to LDS double-buffer
// via global_load_lds; B-fragments (dh/dv stencil + lrelu) built per-lane in
// registers; invalid taps read a zeroed pad slot (offset 400 of each 404-float
// channel plane) so the inner loop is pure fma.
__global__ __launch_bounds__(512, 2) void fused_main(
    const float* __restrict__ x,
    const float* __restrict__ whdw,   // [128][5]
    const float* __restrict__ wvdw,   // [128][5]
    const bf16* __restrict__ Wt,      // [128][256]
    const bf16* __restrict__ W1,      // [32][128]
    const bf16* __restrict__ W2,      // [128][32]
    const float* __restrict__ scalep,
    float* __restrict__ out) {
  __shared__ __align__(16) char smemc[59904];
  float* xs0 = (float*)smemc;                    // [16][404] fp32
  float* xs1 = (float*)(smemc + 25856);          // [16][404] fp32
  float* whs = (float*)(smemc + 51712);          // [128][8] (row-padded)
  float* wvs = (float*)(smemc + 55808);          // [128][8]

  const int tid = threadIdx.x;
  const int w = tid >> 6, lane = tid & 63, ln16 = lane & 15, q = lane >> 4;
  const int hv = q >> 1;        // 0: horizontal stencil, 1: vertical
  const int cb = (q & 1) * 8;   // channel sub-half within 16-ch chunk
  const bool has3 = (w == 0);   // only wave 0 owns the 25th N-tile

  const int bx = blockIdx.x;
  const int wc = bx & 3, hi = (bx >> 2) & 63, b = bx >> 8;
  const size_t xbase = (size_t)b * 13107200 + (size_t)(hi * 5) * 320 + (size_t)(wc * 80);
  const float* gx = x + xbase;

  // stage dw weights (rows padded to 8 floats for b128 reads)
  for (int i = tid; i < 1280; i += 512) {
    int j = (i < 640) ? i : (i - 640);
    int c = j / 5, t = j - c * 5;
    float v = (i < 640) ? whdw[j] : wvdw[j];
    ((i < 640) ? whs : wvs)[c * 8 + t] = v;
  }
  // zero the per-plane pad slots (floats 400..403) of both x buffers
  if (tid < 128) {
    float* bufp = (tid & 64) ? xs1 : xs0;
    int c = (tid & 63) >> 2, p = tid & 3;
    bufp[c * 404 + 400 + p] = 0.f;
  }

  // chunk-invariant per-lane tap addresses (relative to channel plane)
  int ta[4][5];
#pragma unroll
  for (int s = 0; s < 4; ++s) {
    int nt = w + 8 * s;
    int pos = nt * 16 + ln16;
    if (pos > 399) pos = 399;          // invalid tiles: safe dummy
    int a = pos / 80;
    int col = pos - a * 80;
    int aw = col - (col / 5) * 5;
#pragma unroll
    for (int t = 0; t < 5; ++t) {
      int d = t - 2;
      int ah = ((unsigned)(aw + d) < 5u) ? (a * 80 + col + d) : 400;
      int av = ((unsigned)(a + d) < 5u) ? ((a + d) * 80 + col) : 400;
      ta[s][t] = hv ? av : ah;
    }
  }

  // async stage of one 16-channel x chunk: wave w loads channels w and w+8,
  // 100 16B-slots per channel (64-lane call + 36-lane call), LDS base uniform.
  auto stage = [&](int kk, float* buf) {
    const int c0k = kk * 16;
#pragma unroll
    for (int h2 = 0; h2 < 2; ++h2) {
      const int c = w + 8 * h2;
      const float* gc = gx + (size_t)(c0k + c) * 102400;
      float* lb = buf + c * 404;
      {
        int r = lane / 20, c4 = lane - r * 20;
        async_ld16(gc + r * 320 + c4 * 4, lb);
      }
      if (lane < 36) {
        int rem = 64 + lane;
        int r = rem / 20, c4 = rem - r * 20;
        async_ld16(gc + r * 320 + c4 * 4, lb + 256);
      }
    }
  };

  f32x4 acc[4][8];
#pragma unroll
  for (int s = 0; s < 4; ++s)
#pragma unroll
    for (int m = 0; m < 8; ++m) acc[s][m] = (f32x4){0.f, 0.f, 0.f, 0.f};

  stage(0, xs0);

  for (int kk = 0; kk < 8; ++kk) {
    float* cur = (kk & 1) ? xs1 : xs0;
    float* nxt = (kk & 1) ? xs0 : xs1;
    const int c0 = kk * 16;
    __syncthreads();  // drains this chunk's DMA; closes readers of nxt's old data

    // A fragments first (before DMA issue, so MFMA's vmcnt wait doesn't
    // FIFO-drain the prefetch)
    v8bf af[8];
    const int koff = c0 + (q & 1) * 8 + hv * 128;
#pragma unroll
    for (int m = 0; m < 8; ++m)
      af[m] = *(const v8bf*)(Wt + (m * 16 + ln16) * 256 + koff);

    if (kk < 7) stage(kk + 1, nxt);

    // per-lane stencil -> B fragments (pure fma; zero-slot handles masking)
    const float* wb8 = (hv ? wvs : whs) + (c0 + cb) * 8;
    float frag[4][8];
#pragma unroll
    for (int c = 0; c < 8; ++c) {
      const float4 wv4 = *(const float4*)(wb8 + c * 8);
      const float w4v = wb8[c * 8 + 4];
      const float* xp = cur + (cb + c) * 404;
#pragma unroll
      for (int s = 0; s < 4; ++s) {
        if (s == 3 && !has3) continue;
        float d = wv4.x * xp[ta[s][0]];
        d = fmaf(wv4.y, xp[ta[s][1]], d);
        d = fmaf(wv4.z, xp[ta[s][2]], d);
        d = fmaf(wv4.w, xp[ta[s][3]], d);
        frag[s][c] = fmaf(w4v, xp[ta[s][4]], d);
      }
    }
#pragma unroll
    for (int s = 0; s < 4; ++s) {
      if (s == 3 && !has3) break;
      v8bf bv;
#pragma unroll
      for (int c = 0; c < 8; ++c) {
        float d = frag[s][c];
        d = fmaxf(d, 0.f) + 0.1f * fminf(d, 0.f);
        bv[c] = (bf16)d;
      }
#pragma unroll
      for (int m = 0; m < 8; ++m)
        acc[s][m] = MFMA16x16x32(af[m], bv, acc[s][m]);
    }
  }
  __syncthreads();  // all xs/weight readers done; overlay epilogue buffers

  // per-wave private epilogue buffers (no cross-wave traffic, no barriers)
  bf16* es = (bf16*)(smemc + w * 4608);            // [16 pos][144]
  bf16* ts = (bf16*)(smemc + 36864 + w * 1280);    // [16 pos][40]
  const float scl = scalep[0];

#pragma unroll
  for (int s = 0; s < 4; ++s) {
    const int nt = w + 8 * s;
    if (nt < 25) {
      // 1) epi C-frags -> es[pos][o] bf16
#pragma unroll
      for (int m = 0; m < 8; ++m) {
        v4bf v;
        v[0] = (bf16)acc[s][m][0];
        v[1] = (bf16)acc[s][m][1];
        v[2] = (bf16)acc[s][m][2];
        v[3] = (bf16)acc[s][m][3];
        *(v4bf*)(es + ln16 * 144 + m * 16 + q * 4) = v;
      }
      // 2) t = lrelu(Wdm1 @ epi): M=32 (2 tiles), K=128 (4 steps)
      f32x4 tacc[2];
      tacc[0] = (f32x4){0.f, 0.f, 0.f, 0.f};
      tacc[1] = (f32x4){0.f, 0.f, 0.f, 0.f};
#pragma unroll
      for (int ks = 0; ks < 4; ++ks) {
        v8bf bfr = *(const v8bf*)(es + ln16 * 144 + ks * 32 + q * 8);
#pragma unroll
        for (int m2 = 0; m2 < 2; ++m2) {
          v8bf afr = *(const v8bf*)(W1 + (m2 * 16 + ln16) * 128 + ks * 32 + q * 8);
          tacc[m2] = MFMA16x16x32(afr, bfr, tacc[m2]);
        }
      }
      // 3) lrelu(t) -> ts[pos][d] bf16
#pragma unroll
      for (int m2 = 0; m2 < 2; ++m2) {
        v4bf v;
#pragma unroll
        for (int r = 0; r < 4; ++r) {
          float tv = tacc[m2][r];
          tv = fmaxf(tv, 0.f) + 0.1f * fminf(tv, 0.f);
          v[r] = (bf16)tv;
        }
        *(v4bf*)(ts + ln16 * 40 + m2 * 16 + q * 4) = v;
      }
      // 4) dw = Wdm2 @ t; 5) out = x + scale*epi*sigmoid(dw)
      v8bf tb = *(const v8bf*)(ts + ln16 * 40 + q * 8);
      const int pos = nt * 16 + ln16;
      const int a = pos / 80;
      const int col = pos - a * 80;
      const size_t gb = xbase + (size_t)(a * 320 + col);
#pragma unroll
      for (int m = 0; m < 8; ++m) {
        v8bf afr2 = *(const v8bf*)(W2 + (m * 16 + ln16) * 32 + q * 8);
        f32x4 z = {0.f, 0.f, 0.f, 0.f};
        f32x4 dacc = MFMA16x16x32(afr2, tb, z);
#pragma unroll
        for (int r = 0; r < 4; ++r) {
          const int o = m * 16 + q * 4 + r;
          const float sig = 1.0f / (1.0f + __expf(-dacc[r]));
          const size_t g = gb + (size_t)o * 102400;
          out[g] = x[g] + scl * acc[s][m][r] * sig;
        }
      }
    }
  }
}

// ---------------- launcher ----------------
extern "C" void kernel_launch(void* const* d_in, const int* in_sizes, int n_in,
                              void* d_out, int out_size, void* d_ws, size_t ws_size,
                              hipStream_t stream) {
  (void)in_sizes; (void)n_in; (void)out_size; (void)ws_size;
  const float* x     = (const float*)d_in[0];
  const float* whdw  = (const float*)d_in[1];
  const float* whpw  = (const float*)d_in[2];
  const float* wvdw  = (const float*)d_in[3];
  const float* wvpw  = (const float*)d_in[4];
  const float* wdm1  = (const float*)d_in[5];
  const float* wdm2  = (const float*)d_in[6];
  const float* wfuse = (const float*)d_in[7];
  const float* scale = (const float*)d_in[8];

  bf16* Wt = (bf16*)d_ws;          // 128*256 bf16
  bf16* W1 = Wt + 32768;           // 32*128
  bf16* W2 = W1 + 4096;            // 128*32

  prep_wt<<<512, 64, 0, stream>>>(wfuse, whpw, wvpw, Wt);
  prep_dm<<<32, 256, 0, stream>>>(wdm1, wdm2, W1, W2);
  fused_main<<<512, 512, 0, stream>>>(x, whdw, wvdw, Wt, W1, W2, scale, (float*)d_out);
}

// Round 3
// 343.543 us; speedup vs baseline: 1.7092x; 1.7092x over previous
//
#include <hip/hip_runtime.h>
#include <stdint.h>

typedef __bf16 bf16;
typedef __bf16 v8bf __attribute__((ext_vector_type(8)));
typedef __bf16 v4bf __attribute__((ext_vector_type(4)));
typedef float f32x4 __attribute__((ext_vector_type(4)));

#define MFMA16x16x32(a, b, c) __builtin_amdgcn_mfma_f32_16x16x32_bf16((a), (b), (c), 0, 0, 0)

__device__ __forceinline__ void async_ld16(const float* g, float* l) {
  __builtin_amdgcn_global_load_lds(
      (const __attribute__((address_space(1))) uint32_t*)g,
      (__attribute__((address_space(3))) uint32_t*)l, 16, 0, 0);
}

// ---------------- prep kernels ----------------
__global__ __launch_bounds__(64) void prep_wt(const float* __restrict__ wfuse,
                                              const float* __restrict__ whpw,
                                              const float* __restrict__ wvpw,
                                              bf16* __restrict__ Wt) {
  int id = blockIdx.x * 64 + threadIdx.x;  // 32768 total
  int o = id >> 8, k = id & 255, ki = k & 127;
  const float* fr = wfuse + o * 256 + (k < 128 ? 0 : 128);
  const float* pw = (k < 128) ? whpw : wvpw;
  float a0 = 0.f, a1 = 0.f, a2 = 0.f, a3 = 0.f;
#pragma unroll 8
  for (int j = 0; j < 128; j += 4) {
    a0 = fmaf(fr[j + 0], pw[(j + 0) * 128 + ki], a0);
    a1 = fmaf(fr[j + 1], pw[(j + 1) * 128 + ki], a1);
    a2 = fmaf(fr[j + 2], pw[(j + 2) * 128 + ki], a2);
    a3 = fmaf(fr[j + 3], pw[(j + 3) * 128 + ki], a3);
  }
  Wt[o * 256 + k] = (bf16)((a0 + a1) + (a2 + a3));
}

__global__ void prep_dm(const float* __restrict__ wdm1,
                        const float* __restrict__ wdm2,
                        bf16* __restrict__ W1, bf16* __restrict__ W2) {
  int id = blockIdx.x * 256 + threadIdx.x;  // 8192
  if (id < 4096) W1[id] = (bf16)wdm1[id];
  else           W2[id - 4096] = (bf16)wdm2[id - 4096];
}

// ---------------- fused main kernel ----------------
// 512 blocks = (b:2)x(hi:64)x(wchunk:4); tile 5 rows x 80 cols = 400 pos.
// K streamed as 8 chunks of 16 channels; x chunk DMA'd to LDS double-buffer;
// B-fragments (stencil+lrelu) built per-lane in registers, s-tile at a time
// (peak-live minimized: no frag[4][8], no persistent tap array -> no spills).
__global__ __launch_bounds__(512, 2) void fused_main(
    const float* __restrict__ x,
    const float* __restrict__ whdw,   // [128][5]
    const float* __restrict__ wvdw,   // [128][5]
    const bf16* __restrict__ Wt,      // [128][256]
    const bf16* __restrict__ W1,      // [32][128]
    const bf16* __restrict__ W2,      // [128][32]
    const float* __restrict__ scalep,
    float* __restrict__ out) {
  __shared__ __align__(16) char smemc[59904];
  float* xs0 = (float*)smemc;                    // [16][404] fp32
  float* xs1 = (float*)(smemc + 25856);          // [16][404] fp32
  float* whs = (float*)(smemc + 51712);          // [128][8] row-padded
  float* wvs = (float*)(smemc + 55808);          // [128][8]

  const int tid = threadIdx.x;
  const int w = tid >> 6, lane = tid & 63, ln16 = lane & 15, q = lane >> 4;
  const int hv = q >> 1;        // 0: horizontal stencil, 1: vertical
  const int cb = (q & 1) * 8;   // channel sub-half within 16-ch chunk
  const bool has3 = (w == 0);   // only wave 0 owns the 25th N-tile

  const int bx = blockIdx.x;
  const int wc = bx & 3, hi = (bx >> 2) & 63, b = bx >> 8;
  const size_t xbase = (size_t)b * 13107200 + (size_t)(hi * 5) * 320 + (size_t)(wc * 80);
  const float* gx = x + xbase;

  // stage dw weights (rows padded to 8 floats for b128 broadcast reads)
  for (int i = tid; i < 1280; i += 512) {
    int j = (i < 640) ? i : (i - 640);
    int c = j / 5, t = j - c * 5;
    float v = (i < 640) ? whdw[j] : wvdw[j];
    ((i < 640) ? whs : wvs)[c * 8 + t] = v;
  }
  // zero the per-plane pad slots (floats 400..403) of both x buffers
  if (tid < 128) {
    float* bufp = (tid & 64) ? xs1 : xs0;
    int c = (tid & 63) >> 2, p = tid & 3;
    bufp[c * 404 + 400 + p] = 0.f;
  }

  // packed per-s position info: a | col<<8 | aw<<16   (4 regs only)
  int pk[4];
#pragma unroll
  for (int s = 0; s < 4; ++s) {
    int pos = (w + 8 * s) * 16 + ln16;
    if (pos > 399) pos = 399;
    int a = pos / 80;
    int col = pos - a * 80;
    int aw = col - (col / 5) * 5;
    pk[s] = a | (col << 8) | (aw << 16);
  }

  // async stage of one 16-channel x chunk: wave w loads channels w and w+8
  auto stage = [&](int kk, float* buf) {
    const int c0k = kk * 16;
#pragma unroll
    for (int h2 = 0; h2 < 2; ++h2) {
      const int c = w + 8 * h2;
      const float* gc = gx + (size_t)(c0k + c) * 102400;
      float* lb = buf + c * 404;
      {
        int r = lane / 20, c4 = lane - r * 20;
        async_ld16(gc + r * 320 + c4 * 4, lb);
      }
      if (lane < 36) {
        int rem = 64 + lane;
        int r = rem / 20, c4 = rem - r * 20;
        async_ld16(gc + r * 320 + c4 * 4, lb + 256);
      }
    }
  };

  f32x4 acc[4][8];
#pragma unroll
  for (int s = 0; s < 4; ++s)
#pragma unroll
    for (int m = 0; m < 8; ++m) acc[s][m] = (f32x4){0.f, 0.f, 0.f, 0.f};

  stage(0, xs0);

  for (int kk = 0; kk < 8; ++kk) {
    float* cur = (kk & 1) ? xs1 : xs0;
    float* nxt = (kk & 1) ? xs0 : xs1;
    const int c0 = kk * 16;
    __syncthreads();  // drains prev-issued DMA; closes readers of nxt's old data

    // A fragments first (before DMA issue, so MFMA's vmcnt wait doesn't
    // FIFO-drain the prefetch)
    v8bf af[8];
    const int koff = c0 + (q & 1) * 8 + hv * 128;
#pragma unroll
    for (int m = 0; m < 8; ++m)
      af[m] = *(const v8bf*)(Wt + (m * 16 + ln16) * 256 + koff);

    if (kk < 7) stage(kk + 1, nxt);

    const float* wb8 = (hv ? wvs : whs) + (c0 + cb) * 8;
    // stencil + MFMA, one N-tile (s) at a time: only bv + 5 taps live
#pragma unroll
    for (int s = 0; s < 4; ++s) {
      if (s == 3 && !has3) break;
      const int a = pk[s] & 255, col = (pk[s] >> 8) & 255, aw = pk[s] >> 16;
      const int base = a * 80 + col;
      int tap[5];
#pragma unroll
      for (int t = 0; t < 5; ++t) {
        const int d = t - 2;
        const int th = ((unsigned)(aw + d) < 5u) ? (base + d) : 400;
        const int tv = ((unsigned)(a + d) < 5u) ? (base + d * 80) : 400;
        tap[t] = hv ? tv : th;
      }
      v8bf bv;
#pragma unroll
      for (int c = 0; c < 8; ++c) {
        const float4 wv4 = *(const float4*)(wb8 + c * 8);
        const float w4v = wb8[c * 8 + 4];
        const float* xp = cur + (cb + c) * 404;
        float d = wv4.x * xp[tap[0]];
        d = fmaf(wv4.y, xp[tap[1]], d);
        d = fmaf(wv4.z, xp[tap[2]], d);
        d = fmaf(wv4.w, xp[tap[3]], d);
        d = fmaf(w4v, xp[tap[4]], d);
        d = fmaxf(d, 0.f) + 0.1f * fminf(d, 0.f);
        bv[c] = (bf16)d;
      }
#pragma unroll
      for (int m = 0; m < 8; ++m)
        acc[s][m] = MFMA16x16x32(af[m], bv, acc[s][m]);
    }
  }
  __syncthreads();  // all xs/weight readers done; overlay epilogue buffers

  // per-wave private epilogue buffers (no cross-wave traffic, no barriers)
  bf16* es = (bf16*)(smemc + w * 4608);            // [16 pos][144]
  bf16* ts = (bf16*)(smemc + 36864 + w * 1280);    // [16 pos][40]
  const float scl = scalep[0];

#pragma unroll
  for (int s = 0; s < 4; ++s) {
    const int nt = w + 8 * s;
    if (nt < 25) {
      // 1) epi C-frags -> es[pos][o] bf16
#pragma unroll
      for (int m = 0; m < 8; ++m) {
        v4bf v;
        v[0] = (bf16)acc[s][m][0];
        v[1] = (bf16)acc[s][m][1];
        v[2] = (bf16)acc[s][m][2];
        v[3] = (bf16)acc[s][m][3];
        *(v4bf*)(es + ln16 * 144 + m * 16 + q * 4) = v;
      }
      // 2) t = lrelu(Wdm1 @ epi): M=32 (2 tiles), K=128 (4 steps)
      f32x4 tacc[2];
      tacc[0] = (f32x4){0.f, 0.f, 0.f, 0.f};
      tacc[1] = (f32x4){0.f, 0.f, 0.f, 0.f};
#pragma unroll
      for (int ks = 0; ks < 4; ++ks) {
        v8bf bfr = *(const v8bf*)(es + ln16 * 144 + ks * 32 + q * 8);
#pragma unroll
        for (int m2 = 0; m2 < 2; ++m2) {
          v8bf afr = *(const v8bf*)(W1 + (m2 * 16 + ln16) * 128 + ks * 32 + q * 8);
          tacc[m2] = MFMA16x16x32(afr, bfr, tacc[m2]);
        }
      }
      // 3) lrelu(t) -> ts[pos][d] bf16
#pragma unroll
      for (int m2 = 0; m2 < 2; ++m2) {
        v4bf v;
#pragma unroll
        for (int r = 0; r < 4; ++r) {
          float tv = tacc[m2][r];
          tv = fmaxf(tv, 0.f) + 0.1f * fminf(tv, 0.f);
          v[r] = (bf16)tv;
        }
        *(v4bf*)(ts + ln16 * 40 + m2 * 16 + q * 4) = v;
      }
      // 4) dw = Wdm2 @ t; 5) out = x + scale*epi*sigmoid(dw)
      v8bf tb = *(const v8bf*)(ts + ln16 * 40 + q * 8);
      const int pos = nt * 16 + ln16;
      const int a = pos / 80;
      const int col = pos - a * 80;
      const size_t gb = xbase + (size_t)(a * 320 + col);
#pragma unroll
      for (int m = 0; m < 8; ++m) {
        v8bf afr2 = *(const v8bf*)(W2 + (m * 16 + ln16) * 32 + q * 8);
        f32x4 z = {0.f, 0.f, 0.f, 0.f};
        f32x4 dacc = MFMA16x16x32(afr2, tb, z);
#pragma unroll
        for (int r = 0; r < 4; ++r) {
          const int o = m * 16 + q * 4 + r;
          const float sig = 1.0f / (1.0f + __expf(-dacc[r]));
          const size_t g = gb + (size_t)o * 102400;
          out[g] = x[g] + scl * acc[s][m][r] * sig;
        }
      }
    }
  }
}

// ---------------- launcher ----------------
extern "C" void kernel_launch(void* const* d_in, const int* in_sizes, int n_in,
                              void* d_out, int out_size, void* d_ws, size_t ws_size,
                              hipStream_t stream) {
  (void)in_sizes; (void)n_in; (void)out_size; (void)ws_size;
  const float* x     = (const float*)d_in[0];
  const float* whdw  = (const float*)d_in[1];
  const float* whpw  = (const float*)d_in[2];
  const float* wvdw  = (const float*)d_in[3];
  const float* wvpw  = (const float*)d_in[4];
  const float* wdm1  = (const float*)d_in[5];
  const float* wdm2  = (const float*)d_in[6];
  const float* wfuse = (const float*)d_in[7];
  const float* scale = (const float*)d_in[8];

  bf16* Wt = (bf16*)d_ws;          // 128*256 bf16
  bf16* W1 = Wt + 32768;           // 32*128
  bf16* W2 = W1 + 4096;            // 128*32

  prep_wt<<<512, 64, 0, stream>>>(wfuse, whpw, wvpw, Wt);
  prep_dm<<<32, 256, 0, stream>>>(wdm1, wdm2, W1, W2);
  fused_main<<<512, 512, 0, stream>>>(x, whdw, wvdw, Wt, W1, W2, scale, (float*)d_out);
}

// Round 4
// 341.996 us; speedup vs baseline: 1.7169x; 1.0045x over previous
//
#include <hip/hip_runtime.h>
#include <stdint.h>

typedef __bf16 bf16;
typedef __bf16 v8bf __attribute__((ext_vector_type(8)));
typedef __bf16 v4bf __attribute__((ext_vector_type(4)));
typedef float f32x4 __attribute__((ext_vector_type(4)));

#define MFMA16x16x32(a, b, c) __builtin_amdgcn_mfma_f32_16x16x32_bf16((a), (b), (c), 0, 0, 0)

__device__ __forceinline__ void async_ld16(const float* g, float* l) {
  __builtin_amdgcn_global_load_lds(
      (const __attribute__((address_space(1))) uint32_t*)g,
      (__attribute__((address_space(3))) uint32_t*)l, 16, 0, 0);
}

// ---------------- prep kernels ----------------
__global__ __launch_bounds__(64) void prep_wt(const float* __restrict__ wfuse,
                                              const float* __restrict__ whpw,
                                              const float* __restrict__ wvpw,
                                              bf16* __restrict__ Wt) {
  int id = blockIdx.x * 64 + threadIdx.x;  // 32768 total
  int o = id >> 8, k = id & 255, ki = k & 127;
  const float* fr = wfuse + o * 256 + (k < 128 ? 0 : 128);
  const float* pw = (k < 128) ? whpw : wvpw;
  float a0 = 0.f, a1 = 0.f, a2 = 0.f, a3 = 0.f;
#pragma unroll 8
  for (int j = 0; j < 128; j += 4) {
    a0 = fmaf(fr[j + 0], pw[(j + 0) * 128 + ki], a0);
    a1 = fmaf(fr[j + 1], pw[(j + 1) * 128 + ki], a1);
    a2 = fmaf(fr[j + 2], pw[(j + 2) * 128 + ki], a2);
    a3 = fmaf(fr[j + 3], pw[(j + 3) * 128 + ki], a3);
  }
  Wt[o * 256 + k] = (bf16)((a0 + a1) + (a2 + a3));
}

__global__ void prep_dm(const float* __restrict__ wdm1,
                        const float* __restrict__ wdm2,
                        bf16* __restrict__ W1, bf16* __restrict__ W2) {
  int id = blockIdx.x * 256 + threadIdx.x;  // 8192
  if (id < 4096) W1[id] = (bf16)wdm1[id];
  else           W2[id - 4096] = (bf16)wdm2[id - 4096];
}

// ---------------- fused main kernel ----------------
// 1024 blocks = (b:2)x(hi:64)x(wchunk:8); tile 5 rows x 40 cols = 200 pos.
// acc[2][8] = 64 regs -> fits 128-reg budget -> 2 blocks/CU (4 waves/SIMD)
// for latency hiding + barrier-phase interleave between the two blocks.
// N-tiles of 16: 13 valid (tile 12 half); wave w owns tiles {w, w+8<=12}.
__global__ __launch_bounds__(512, 4) void fused_main(
    const float* __restrict__ x,
    const float* __restrict__ whdw,   // [128][5]
    const float* __restrict__ wvdw,   // [128][5]
    const bf16* __restrict__ Wt,      // [128][256]
    const bf16* __restrict__ W1,      // [32][128]
    const bf16* __restrict__ W2,      // [128][32]
    const float* __restrict__ scalep,
    float* __restrict__ out) {
  __shared__ __align__(16) char smemc[47104];
  float* xs0 = (float*)smemc;                    // [16][204] fp32 (13056 B)
  float* xs1 = (float*)(smemc + 13056);          // [16][204]
  float* whs = (float*)(smemc + 26112);          // [128][8] row-padded
  float* wvs = (float*)(smemc + 30208);          // [128][8]

  const int tid = threadIdx.x;
  const int w = tid >> 6, lane = tid & 63, ln16 = lane & 15, q = lane >> 4;
  const int hv = q >> 1;        // 0: horizontal stencil, 1: vertical
  const int cb = (q & 1) * 8;   // channel sub-half within 16-ch chunk
  const bool has1 = (w <= 4);   // s=1 tile (w+8) valid only if <=12

  const int bx = blockIdx.x;
  const int wc = bx & 7, hi = (bx >> 3) & 63, b = bx >> 9;
  const size_t xbase = (size_t)b * 13107200 + (size_t)(hi * 5) * 320 + (size_t)(wc * 40);
  const float* gx = x + xbase;

  // stage dw weights (rows padded to 8 floats for b128 broadcast reads)
  for (int i = tid; i < 1280; i += 512) {
    int j = (i < 640) ? i : (i - 640);
    int c = j / 5, t = j - c * 5;
    float v = (i < 640) ? whdw[j] : wvdw[j];
    ((i < 640) ? whs : wvs)[c * 8 + t] = v;
  }
  // zero the per-plane pad slots (floats 200..203) of both x buffers
  if (tid < 128) {
    float* bufp = (tid & 64) ? xs1 : xs0;
    int c = (tid & 63) >> 2, p = tid & 3;
    bufp[c * 204 + 200 + p] = 0.f;
  }

  // packed per-s position info: a | col<<8 | aw<<16
  int pk[2];
#pragma unroll
  for (int s = 0; s < 2; ++s) {
    int pos = (w + 8 * s) * 16 + ln16;
    if (pos > 199) pos = 199;
    int a = pos / 40;
    int col = pos - a * 40;
    int aw = col - (col / 5) * 5;
    pk[s] = a | (col << 8) | (aw << 16);
  }

  // async stage of one 16-channel x chunk: wave w loads channels w and w+8;
  // 50 16B-slots per channel (lanes 0..49), LDS base wave-uniform.
  auto stage = [&](int kk, float* buf) {
    const int c0k = kk * 16;
#pragma unroll
    for (int h2 = 0; h2 < 2; ++h2) {
      const int c = w + 8 * h2;
      const float* gc = gx + (size_t)(c0k + c) * 102400;
      float* lb = buf + c * 204;
      if (lane < 50) {
        int r = lane / 10, c4 = lane - r * 10;
        async_ld16(gc + r * 320 + c4 * 4, lb);
      }
    }
  };

  f32x4 acc[2][8];
#pragma unroll
  for (int s = 0; s < 2; ++s)
#pragma unroll
    for (int m = 0; m < 8; ++m) acc[s][m] = (f32x4){0.f, 0.f, 0.f, 0.f};

  stage(0, xs0);

  for (int kk = 0; kk < 8; ++kk) {
    float* cur = (kk & 1) ? xs1 : xs0;
    float* nxt = (kk & 1) ? xs0 : xs1;
    const int c0 = kk * 16;
    __syncthreads();  // drains cur's DMA; closes readers of nxt's old data

    if (kk < 7) stage(kk + 1, nxt);

    // stencil + lrelu -> B fragments (zero-pad slot handles masking)
    const float* wb8 = (hv ? wvs : whs) + (c0 + cb) * 8;
    v8bf bvs[2];
#pragma unroll
    for (int s = 0; s < 2; ++s) {
      if (s == 1 && !has1) break;
      const int a = pk[s] & 255, col = (pk[s] >> 8) & 255, aw = pk[s] >> 16;
      const int base = a * 40 + col;
      int tap[5];
#pragma unroll
      for (int t = 0; t < 5; ++t) {
        const int d = t - 2;
        const int th = ((unsigned)(aw + d) < 5u) ? (base + d) : 200;
        const int tv = ((unsigned)(a + d) < 5u) ? (base + d * 40) : 200;
        tap[t] = hv ? tv : th;
      }
#pragma unroll 4
      for (int c = 0; c < 8; ++c) {
        const float4 wv4 = *(const float4*)(wb8 + c * 8);
        const float w4v = wb8[c * 8 + 4];
        const float* xp = cur + (cb + c) * 204;
        float d = wv4.x * xp[tap[0]];
        d = fmaf(wv4.y, xp[tap[1]], d);
        d = fmaf(wv4.z, xp[tap[2]], d);
        d = fmaf(wv4.w, xp[tap[3]], d);
        d = fmaf(w4v, xp[tap[4]], d);
        d = fmaxf(d, 0.f) + 0.1f * fminf(d, 0.f);
        bvs[s][c] = (bf16)d;
      }
    }

    // A fragments after stencil (short liveness; latency overlaps across waves)
    v8bf af[8];
    const int koff = c0 + (q & 1) * 8 + hv * 128;
#pragma unroll
    for (int m = 0; m < 8; ++m)
      af[m] = *(const v8bf*)(Wt + (m * 16 + ln16) * 256 + koff);
#pragma unroll
    for (int m = 0; m < 8; ++m)
      acc[0][m] = MFMA16x16x32(af[m], bvs[0], acc[0][m]);
    if (has1) {
#pragma unroll
      for (int m = 0; m < 8; ++m)
        acc[1][m] = MFMA16x16x32(af[m], bvs[1], acc[1][m]);
    }
  }
  __syncthreads();  // all xs/weight readers done; overlay epilogue buffers

  // per-wave private epilogue buffers (no cross-wave traffic, no barriers)
  bf16* es = (bf16*)(smemc + w * 4608);            // [16 pos][144]
  bf16* ts = (bf16*)(smemc + 36864 + w * 1280);    // [16 pos][40]
  const float scl = scalep[0];

#pragma unroll
  for (int s = 0; s < 2; ++s) {
    const int nt = w + 8 * s;
    if (nt <= 12) {
      // 1) epi C-frags -> es[pos][o] bf16
#pragma unroll
      for (int m = 0; m < 8; ++m) {
        v4bf v;
        v[0] = (bf16)acc[s][m][0];
        v[1] = (bf16)acc[s][m][1];
        v[2] = (bf16)acc[s][m][2];
        v[3] = (bf16)acc[s][m][3];
        *(v4bf*)(es + ln16 * 144 + m * 16 + q * 4) = v;
      }
      // 2) t = lrelu(Wdm1 @ epi): M=32 (2 tiles), K=128 (4 steps)
      f32x4 tacc[2];
      tacc[0] = (f32x4){0.f, 0.f, 0.f, 0.f};
      tacc[1] = (f32x4){0.f, 0.f, 0.f, 0.f};
#pragma unroll
      for (int ks = 0; ks < 4; ++ks) {
        v8bf bfr = *(const v8bf*)(es + ln16 * 144 + ks * 32 + q * 8);
#pragma unroll
        for (int m2 = 0; m2 < 2; ++m2) {
          v8bf afr = *(const v8bf*)(W1 + (m2 * 16 + ln16) * 128 + ks * 32 + q * 8);
          tacc[m2] = MFMA16x16x32(afr, bfr, tacc[m2]);
        }
      }
      // 3) lrelu(t) -> ts[pos][d] bf16
#pragma unroll
      for (int m2 = 0; m2 < 2; ++m2) {
        v4bf v;
#pragma unroll
        for (int r = 0; r < 4; ++r) {
          float tv = tacc[m2][r];
          tv = fmaxf(tv, 0.f) + 0.1f * fminf(tv, 0.f);
          v[r] = (bf16)tv;
        }
        *(v4bf*)(ts + ln16 * 40 + m2 * 16 + q * 4) = v;
      }
      // 4) dw = Wdm2 @ t; 5) out = x + scale*epi*sigmoid(dw)
      v8bf tb = *(const v8bf*)(ts + ln16 * 40 + q * 8);
      const int pos = nt * 16 + ln16;
      const bool valid = (pos < 200);
      const int a = pos / 40;
      const int col = pos - a * 40;
      const size_t gb = xbase + (size_t)(a * 320 + col);
#pragma unroll
      for (int m = 0; m < 8; ++m) {
        v8bf afr2 = *(const v8bf*)(W2 + (m * 16 + ln16) * 32 + q * 8);
        f32x4 z = {0.f, 0.f, 0.f, 0.f};
        f32x4 dacc = MFMA16x16x32(afr2, tb, z);
        if (valid) {
#pragma unroll
          for (int r = 0; r < 4; ++r) {
            const int o = m * 16 + q * 4 + r;
            const float sig = 1.0f / (1.0f + __expf(-dacc[r]));
            const size_t g = gb + (size_t)o * 102400;
            out[g] = x[g] + scl * acc[s][m][r] * sig;
          }
        }
      }
    }
  }
}

// ---------------- launcher ----------------
extern "C" void kernel_launch(void* const* d_in, const int* in_sizes, int n_in,
                              void* d_out, int out_size, void* d_ws, size_t ws_size,
                              hipStream_t stream) {
  (void)in_sizes; (void)n_in; (void)out_size; (void)ws_size;
  const float* x     = (const float*)d_in[0];
  const float* whdw  = (const float*)d_in[1];
  const float* whpw  = (const float*)d_in[2];
  const float* wvdw  = (const float*)d_in[3];
  const float* wvpw  = (const float*)d_in[4];
  const float* wdm1  = (const float*)d_in[5];
  const float* wdm2  = (const float*)d_in[6];
  const float* wfuse = (const float*)d_in[7];
  const float* scale = (const float*)d_in[8];

  bf16* Wt = (bf16*)d_ws;          // 128*256 bf16
  bf16* W1 = Wt + 32768;           // 32*128
  bf16* W2 = W1 + 4096;            // 128*32

  prep_wt<<<512, 64, 0, stream>>>(wfuse, whpw, wvpw, Wt);
  prep_dm<<<32, 256, 0, stream>>>(wdm1, wdm2, W1, W2);
  fused_main<<<1024, 512, 0, stream>>>(x, whdw, wvdw, Wt, W1, W2, scale, (float*)d_out);
}